// Round 16
// baseline (212.720 us; speedup 1.0000x reference)
//
#include <hip/hip_runtime.h>
#include <math.h>
#include <stdint.h>

#define NB 16
#define NC 256
#define NN 4096
#define ND 32

typedef __bf16 bf16_t;
typedef __bf16 bf16x4 __attribute__((ext_vector_type(4)));
typedef __bf16 bf16x8 __attribute__((ext_vector_type(8)));
typedef float  f32x4  __attribute__((ext_vector_type(4)));
typedef float  f32x16 __attribute__((ext_vector_type(16)));

#define AS_GLOBAL __attribute__((address_space(1)))
#define AS_LDS    __attribute__((address_space(3)))

// ---------------------------------------------------------------------------
// Kernel 0: convert weights to bf16 (+ lo residuals for q/k rows).
// Wq rows pre-scaled by log2(e) so attention uses exp2 directly.
// ---------------------------------------------------------------------------
__global__ __launch_bounds__(256) void wconv(
    const float* __restrict__ Wq, const float* __restrict__ Wk,
    const float* __restrict__ Wv, bf16_t* __restrict__ Wb, bf16_t* __restrict__ Wlo)
{
    int i = blockIdx.x * 256 + threadIdx.x;
    if (i >= 320 * 256) return;
    int row = i >> 8, c = i & 255;
    float v;
    if (row < 256)      v = Wv[(row      ) * 256 + c];
    else if (row < 288) v = Wq[(row - 256) * 256 + c] * 1.44269504088896340736f;
    else                v = Wk[(row - 288) * 256 + c];
    bf16_t h = (bf16_t)v;
    Wb[i] = h;
    if (row >= 256) Wlo[(row - 256) * 256 + c] = (bf16_t)(v - (float)h);
}

// ---------------------------------------------------------------------------
// Kernel 1: fused q/k/v projection as one MFMA GEMM (unchanged, ~8 us).
// ---------------------------------------------------------------------------
#define BN_P  128
#define KSTEP 64
#define XPAD  130

__global__ __launch_bounds__(512) void proj_mfma(
    const float* __restrict__ x, const bf16_t* __restrict__ Wb,
    const bf16_t* __restrict__ Wlo,
    bf16_t* __restrict__ Pqb, bf16_t* __restrict__ Pkb, bf16_t* __restrict__ Vn)
{
    __shared__ float xt[KSTEP][XPAD];

    const int b  = blockIdx.x >> 5;
    const int n0 = (blockIdx.x & 31) * BN_P;
    const int tid  = threadIdx.x;
    const int lane = tid & 63;
    const int w    = tid >> 6;
    const int mstrip = w >> 1;
    const int nh     = w & 1;
    const int llo = lane & 15, lhi = lane >> 4;
    const bool qkwave = (mstrip == 3);

    const float* xb = x + (size_t)b * NC * NN + n0;

    f32x4 acc[5][4];
    #pragma unroll
    for (int mf = 0; mf < 5; ++mf)
        #pragma unroll
        for (int nf = 0; nf < 4; ++nf)
            acc[mf][nf] = (f32x4){0.f,0.f,0.f,0.f};

    for (int k0 = 0; k0 < NC; k0 += KSTEP) {
        #pragma unroll
        for (int p = 0; p < 4; ++p) {
            int idx = p * 512 + tid;
            int c   = idx >> 5;
            int nn  = (idx & 31) << 2;
            float4 v = *(const float4*)(xb + (size_t)(k0 + c) * NN + nn);
            *(float2*)&xt[c][nn]     = make_float2(v.x, v.y);
            *(float2*)&xt[c][nn + 2] = make_float2(v.z, v.w);
        }
        __syncthreads();

        #pragma unroll
        for (int ks = 0; ks < 2; ++ks) {
            bf16x8 Ah[5], Al[4];
            #pragma unroll
            for (int mf = 0; mf < 5; ++mf) {
                int row = mstrip * 80 + mf * 16 + llo;
                Ah[mf] = *(const bf16x8*)(Wb + (size_t)row * NC + k0 + ks * 32 + lhi * 8);
            }
            if (qkwave) {
                #pragma unroll
                for (int mf = 1; mf < 5; ++mf) {
                    int row = mstrip * 80 + mf * 16 + llo;
                    Al[mf-1] = *(const bf16x8*)(Wlo + (size_t)(row - 256) * NC
                                                + k0 + ks * 32 + lhi * 8);
                }
            }

            #pragma unroll
            for (int nf = 0; nf < 4; ++nf) {
                const int n  = nh * 64 + nf * 16 + llo;
                const int cb = ks * 32 + lhi * 8;
                bf16x8 bh, bl;
                #pragma unroll
                for (int j = 0; j < 8; ++j) {
                    float f = xt[cb + j][n];
                    bf16_t h = (bf16_t)f;
                    bh[j] = h;
                    if (qkwave) bl[j] = (bf16_t)(f - (float)h);
                }
                #pragma unroll
                for (int mf = 0; mf < 5; ++mf)
                    acc[mf][nf] = __builtin_amdgcn_mfma_f32_16x16x32_bf16(
                                      Ah[mf], bh, acc[mf][nf], 0, 0, 0);
                if (qkwave) {
                    #pragma unroll
                    for (int mf = 1; mf < 5; ++mf) {
                        acc[mf][nf] = __builtin_amdgcn_mfma_f32_16x16x32_bf16(
                                          Al[mf-1], bh, acc[mf][nf], 0, 0, 0);
                        acc[mf][nf] = __builtin_amdgcn_mfma_f32_16x16x32_bf16(
                                          Ah[mf], bl, acc[mf][nf], 0, 0, 0);
                    }
                }
            }
        }
        __syncthreads();
    }

    #pragma unroll
    for (int mf = 0; mf < 5; ++mf) {
        const int rowbase = mstrip * 80 + mf * 16 + lhi * 4;
        #pragma unroll
        for (int nf = 0; nf < 4; ++nf) {
            const int n = n0 + nh * 64 + nf * 16 + llo;
            if (rowbase < 256) {
                #pragma unroll
                for (int r = 0; r < 4; ++r)
                    Vn[((size_t)b * NC + rowbase + r) * NN + n] = (bf16_t)acc[mf][nf][r];
            } else {
                const int d = rowbase - 256;
                bf16x4 q4;
                #pragma unroll
                for (int r = 0; r < 4; ++r) q4[r] = (bf16_t)acc[mf][nf][r];
                if (d < 32) *(bf16x4*)(Pqb + ((size_t)b * NN + n) * ND + d) = q4;
                else        *(bf16x4*)(Pkb + ((size_t)b * NN + n) * ND + d - 32) = q4;
            }
        }
    }
}

// ---------------------------------------------------------------------------
// Kernel 2: GEMM-shaped attention, R14 interleave + 32x32x16 PV MFMAs.
// Block = (batch, 256-m chunk), 8 waves, 1 block/CU, 128 KB LDS.
// Step t: pv_half0(t) | stageV(t+1)+qk(t+1) | loadK(t+2) | pv_half1(t) | bar.
// QK stays 16x16x32 (per-lane row layout feeds exp2 path).
// PV uses 32x32x16: per kstep (k=16): 2 pf + 4 va b128 reads + 8 MFMA;
// 4 ksteps/step = 32 MFMA/wave (was 64 of 16x16x32). A-row = lane&31 so
// row&7 == lane&7 and the XOR swizzle involution is unchanged.
// C/D layout (verified, guide m74/m101): col=lane&31,
// row=(reg&3)+8*(reg>>2)+4*(lane>>5).
// ---------------------------------------------------------------------------
__global__ __launch_bounds__(512, 2) void attn_mfma(
    const bf16_t* __restrict__ Pqb,   // keys    K [B][N][32]
    const bf16_t* __restrict__ Pkb,   // queries Q [B][N][32] (pre-scaled log2e)
    const bf16_t* __restrict__ Vn,    // V [B][C][N]
    const float* __restrict__ x,
    const float* __restrict__ gamma_p,
    float* __restrict__ y)
{
    __shared__ bf16_t vlds[2][256*64];    // 64 KB V tiles, swizzled
    __shared__ bf16_t plds[2][256*64];    // 64 KB P tiles, swizzled

    const int wg  = blockIdx.x;
    const int swb = (wg & 7) * 32 + (wg >> 3);
    const int b   = swb >> 4;
    const int m0  = (swb & 15) << 8;

    const int tid  = threadIdx.x;
    const int lane = tid & 63;
    const int w    = tid >> 6;            // 0..7
    const int lhi  = lane >> 4;           // 16x16 frag k-group (QK path)
    const int llo  = lane & 15;
    const int l31  = lane & 31;           // 32x32 frag row/col (PV path)
    const int lhi5 = lane >> 5;           // 32x32 frag k-group
    const int wc   = w & 3;               // PV m-quarter (64 m)
    const int eh   = w >> 2;              // PV e-half (128 e)

    const bf16_t* Kbase = Pqb + (size_t)b * NN * ND;
    const bf16_t* Vball = Vn  + (size_t)b * NC * NN;

    bf16x8 qa[2];
    #pragma unroll
    for (int mq = 0; mq < 2; ++mq)
        qa[mq] = *(const bf16x8*)(Pkb + ((size_t)(b*NN + m0 + w*32 + mq*16 + llo)) * ND + lhi*8);

    f32x16 acc[4][2];                     // [etile(32e)][mtile(32m)] = 128 regs
    #pragma unroll
    for (int et2 = 0; et2 < 4; ++et2)
        #pragma unroll
        for (int mt2 = 0; mt2 < 2; ++mt2)
            #pragma unroll
            for (int j = 0; j < 16; ++j)
                acc[et2][mt2][j] = 0.f;

    float ps[2] = {0.f, 0.f};
    bf16x8 kb[4];
    const int swz = (lane & 7) << 4;      // == (llo&7)<<4 == (l31&7)<<4

    const int r8  = lane >> 3;
    const int nsw = 8 * ((lane & 7) ^ r8);
    auto stageV = [&](int tt, int bufw) {
        #pragma unroll
        for (int i = 0; i < 4; ++i) {
            const int row0 = w*32 + i*8;
            const bf16_t* src = Vball + (size_t)(row0 + r8) * NN + tt*64 + nsw;
            bf16_t* dst = &vlds[bufw][row0 * 64];
            __builtin_amdgcn_global_load_lds(
                (const AS_GLOBAL unsigned int*)src,
                (AS_LDS unsigned int*)dst, 16, 0, 0);
        }
    };

    auto loadK = [&](int tt) {
        #pragma unroll
        for (int nt = 0; nt < 4; ++nt)
            kb[nt] = *(const bf16x8*)(Kbase + (size_t)(tt*64 + nt*16 + llo) * ND + lhi*8);
    };

    auto qk_phase = [&](int bufw) {
        f32x4 s[4][2];
        #pragma unroll
        for (int nt = 0; nt < 4; ++nt)
            #pragma unroll
            for (int mq = 0; mq < 2; ++mq)
                s[nt][mq] = __builtin_amdgcn_mfma_f32_16x16x32_bf16(kb[nt], qa[mq],
                                (f32x4){0.f,0.f,0.f,0.f}, 0, 0, 0);
        char* base = (char*)&plds[bufw][0] + (size_t)(w*32 + llo) * 128;
        #pragma unroll
        for (int mq = 0; mq < 2; ++mq)
            #pragma unroll
            for (int nt = 0; nt < 4; ++nt) {
                bf16x4 q4;
                #pragma unroll
                for (int r = 0; r < 4; ++r) {
                    float p = __builtin_amdgcn_exp2f(s[nt][mq][r]);
                    ps[mq] += p;
                    q4[r] = (bf16_t)p;
                }
                *(bf16x4*)(base + mq*2048 + ((nt*32 + lhi*8) ^ swz)) = q4;
            }
    };

    // one half of PV: ksteps {2h, 2h+1}; per kstep 2 pf + 4 va reads + 8 MFMA
    auto pv_half = [&](int bufw, int h) {
        char* vb = (char*)&vlds[bufw][0];
        char* pb = (char*)&plds[bufw][0];
        #pragma unroll
        for (int ks4 = 2*h; ks4 < 2*h + 2; ++ks4) {
            const int cofs = (ks4*32 + lhi5*16) ^ swz;   // k-bytes, swizzled
            bf16x8 pf[2];
            #pragma unroll
            for (int mt2 = 0; mt2 < 2; ++mt2)
                pf[mt2] = *(const bf16x8*)(pb + (size_t)(wc*64 + mt2*32 + l31)*128 + cofs);
            bf16x8 va[4];
            #pragma unroll
            for (int et2 = 0; et2 < 4; ++et2)
                va[et2] = *(const bf16x8*)(vb + (size_t)(eh*128 + et2*32 + l31)*128 + cofs);
            __builtin_amdgcn_s_setprio(1);
            #pragma unroll
            for (int et2 = 0; et2 < 4; ++et2)
                #pragma unroll
                for (int mt2 = 0; mt2 < 2; ++mt2)
                    acc[et2][mt2] = __builtin_amdgcn_mfma_f32_32x32x16_bf16(
                                        va[et2], pf[mt2], acc[et2][mt2], 0, 0, 0);
            __builtin_amdgcn_s_setprio(0);
        }
    };

    // ---- prologue: V(0) DMA, K(0), P(0) -> buf0, K(1) in flight
    stageV(0, 0);
    loadK(0);
    qk_phase(0);
    loadK(1);
    __syncthreads();                      // V(0) + P(0) ready

    // ---- main loop: one barrier per step, producer phase between PV halves
    for (int t = 0; t < NN/64; ++t) {
        const int cur = t & 1;
        const int nxt = cur ^ 1;
        pv_half(cur, 0);                  // ksteps 0-1 (16 MFMA)
        if (t < NN/64 - 1) {
            stageV(t + 1, nxt);           // async DMA, drained at barrier
            qk_phase(nxt);                // kb holds K(t+1)
        }
        if (t < NN/64 - 2) loadK(t + 2);
        pv_half(cur, 1);                  // ksteps 2-3 (16 MFMA)
        __syncthreads();
    }

    // ---- denominators (alias dead vlds as float scratch)
    float* sum_lds = (float*)&vlds[0][0];
    #pragma unroll
    for (int mq = 0; mq < 2; ++mq) {
        float v = ps[mq];
        v += __shfl_xor(v, 16, 64);
        v += __shfl_xor(v, 32, 64);
        if (lhi == 0) sum_lds[w*32 + mq*16 + llo] = v;
    }
    __syncthreads();

    const float gamma = gamma_p[0];
    float inv2[2];
    #pragma unroll
    for (int mt2 = 0; mt2 < 2; ++mt2)
        inv2[mt2] = 1.f / sum_lds[wc*64 + mt2*32 + l31];

    // 32x32 C/D layout: col(m) = lane&31, row(e) = (r&3) + 8*(r>>2) + 4*(lane>>5)
    #pragma unroll
    for (int et2 = 0; et2 < 4; ++et2)
        #pragma unroll
        for (int mt2 = 0; mt2 < 2; ++mt2) {
            const int m = m0 + wc*64 + mt2*32 + l31;
            #pragma unroll
            for (int r = 0; r < 16; ++r) {
                const int e = eh*128 + et2*32 + (r & 3) + 8*(r >> 2) + 4*lhi5;
                size_t idx = ((size_t)(b*NC + e)) * NN + m;
                y[idx] = gamma * (acc[et2][mt2][r] * inv2[mt2]) + x[idx];
            }
        }
}

// ---------------------------------------------------------------------------
extern "C" void kernel_launch(void* const* d_in, const int* in_sizes, int n_in,
                              void* d_out, int out_size, void* d_ws, size_t ws_size,
                              hipStream_t stream) {
    const float* x     = (const float*)d_in[0];
    const float* Wq    = (const float*)d_in[1];
    const float* Wk    = (const float*)d_in[2];
    const float* Wv    = (const float*)d_in[3];
    const float* gamma = (const float*)d_in[4];
    float* y = (float*)d_out;

    bf16_t* Pqb = (bf16_t*)d_ws;
    bf16_t* Pkb = Pqb + (size_t)NB * NN * ND;
    bf16_t* Vnb = Pkb + (size_t)NB * NN * ND;
    bf16_t* Wb  = Vnb + (size_t)NB * NC * NN;
    bf16_t* Wlo = Wb  + 320 * 256;

    wconv<<<320, 256, 0, stream>>>(Wq, Wk, Wv, Wb, Wlo);
    proj_mfma<<<NB * (NN / BN_P), 512, 0, stream>>>(x, Wb, Wlo, Pqb, Pkb, Vnb);
    attn_mfma<<<NB * (NN/256), 512, 0, stream>>>(Pqb, Pkb, Vnb, x, gamma, y);
}

// Round 17
// 201.626 us; speedup vs baseline: 1.0550x; 1.0550x over previous
//
#include <hip/hip_runtime.h>
#include <math.h>
#include <stdint.h>

#define NB 16
#define NC 256
#define NN 4096
#define ND 32

typedef __bf16 bf16_t;
typedef __bf16 bf16x4 __attribute__((ext_vector_type(4)));
typedef __bf16 bf16x8 __attribute__((ext_vector_type(8)));
typedef float  f32x4  __attribute__((ext_vector_type(4)));

#define AS_GLOBAL __attribute__((address_space(1)))
#define AS_LDS    __attribute__((address_space(3)))

// ---------------------------------------------------------------------------
// Kernel 0: convert weights to bf16 (+ lo residuals for q/k rows).
// Wq rows pre-scaled by log2(e) so attention uses exp2 directly.
// ---------------------------------------------------------------------------
__global__ __launch_bounds__(256) void wconv(
    const float* __restrict__ Wq, const float* __restrict__ Wk,
    const float* __restrict__ Wv, bf16_t* __restrict__ Wb, bf16_t* __restrict__ Wlo)
{
    int i = blockIdx.x * 256 + threadIdx.x;
    if (i >= 320 * 256) return;
    int row = i >> 8, c = i & 255;
    float v;
    if (row < 256)      v = Wv[(row      ) * 256 + c];
    else if (row < 288) v = Wq[(row - 256) * 256 + c] * 1.44269504088896340736f;
    else                v = Wk[(row - 288) * 256 + c];
    bf16_t h = (bf16_t)v;
    Wb[i] = h;
    if (row >= 256) Wlo[(row - 256) * 256 + c] = (bf16_t)(v - (float)h);
}

// ---------------------------------------------------------------------------
// Kernel 1: fused q/k/v projection as one MFMA GEMM (unchanged, ~8 us).
// ---------------------------------------------------------------------------
#define BN_P  128
#define KSTEP 64
#define XPAD  130

__global__ __launch_bounds__(512) void proj_mfma(
    const float* __restrict__ x, const bf16_t* __restrict__ Wb,
    const bf16_t* __restrict__ Wlo,
    bf16_t* __restrict__ Pqb, bf16_t* __restrict__ Pkb, bf16_t* __restrict__ Vn)
{
    __shared__ float xt[KSTEP][XPAD];

    const int b  = blockIdx.x >> 5;
    const int n0 = (blockIdx.x & 31) * BN_P;
    const int tid  = threadIdx.x;
    const int lane = tid & 63;
    const int w    = tid >> 6;
    const int mstrip = w >> 1;
    const int nh     = w & 1;
    const int llo = lane & 15, lhi = lane >> 4;
    const bool qkwave = (mstrip == 3);

    const float* xb = x + (size_t)b * NC * NN + n0;

    f32x4 acc[5][4];
    #pragma unroll
    for (int mf = 0; mf < 5; ++mf)
        #pragma unroll
        for (int nf = 0; nf < 4; ++nf)
            acc[mf][nf] = (f32x4){0.f,0.f,0.f,0.f};

    for (int k0 = 0; k0 < NC; k0 += KSTEP) {
        #pragma unroll
        for (int p = 0; p < 4; ++p) {
            int idx = p * 512 + tid;
            int c   = idx >> 5;
            int nn  = (idx & 31) << 2;
            float4 v = *(const float4*)(xb + (size_t)(k0 + c) * NN + nn);
            *(float2*)&xt[c][nn]     = make_float2(v.x, v.y);
            *(float2*)&xt[c][nn + 2] = make_float2(v.z, v.w);
        }
        __syncthreads();

        #pragma unroll
        for (int ks = 0; ks < 2; ++ks) {
            bf16x8 Ah[5], Al[4];
            #pragma unroll
            for (int mf = 0; mf < 5; ++mf) {
                int row = mstrip * 80 + mf * 16 + llo;
                Ah[mf] = *(const bf16x8*)(Wb + (size_t)row * NC + k0 + ks * 32 + lhi * 8);
            }
            if (qkwave) {
                #pragma unroll
                for (int mf = 1; mf < 5; ++mf) {
                    int row = mstrip * 80 + mf * 16 + llo;
                    Al[mf-1] = *(const bf16x8*)(Wlo + (size_t)(row - 256) * NC
                                                + k0 + ks * 32 + lhi * 8);
                }
            }

            #pragma unroll
            for (int nf = 0; nf < 4; ++nf) {
                const int n  = nh * 64 + nf * 16 + llo;
                const int cb = ks * 32 + lhi * 8;
                bf16x8 bh, bl;
                #pragma unroll
                for (int j = 0; j < 8; ++j) {
                    float f = xt[cb + j][n];
                    bf16_t h = (bf16_t)f;
                    bh[j] = h;
                    if (qkwave) bl[j] = (bf16_t)(f - (float)h);
                }
                #pragma unroll
                for (int mf = 0; mf < 5; ++mf)
                    acc[mf][nf] = __builtin_amdgcn_mfma_f32_16x16x32_bf16(
                                      Ah[mf], bh, acc[mf][nf], 0, 0, 0);
                if (qkwave) {
                    #pragma unroll
                    for (int mf = 1; mf < 5; ++mf) {
                        acc[mf][nf] = __builtin_amdgcn_mfma_f32_16x16x32_bf16(
                                          Al[mf-1], bh, acc[mf][nf], 0, 0, 0);
                        acc[mf][nf] = __builtin_amdgcn_mfma_f32_16x16x32_bf16(
                                          Ah[mf], bl, acc[mf][nf], 0, 0, 0);
                    }
                }
            }
        }
        __syncthreads();
    }

    #pragma unroll
    for (int mf = 0; mf < 5; ++mf) {
        const int rowbase = mstrip * 80 + mf * 16 + lhi * 4;
        #pragma unroll
        for (int nf = 0; nf < 4; ++nf) {
            const int n = n0 + nh * 64 + nf * 16 + llo;
            if (rowbase < 256) {
                #pragma unroll
                for (int r = 0; r < 4; ++r)
                    Vn[((size_t)b * NC + rowbase + r) * NN + n] = (bf16_t)acc[mf][nf][r];
            } else {
                const int d = rowbase - 256;
                bf16x4 q4;
                #pragma unroll
                for (int r = 0; r < 4; ++r) q4[r] = (bf16_t)acc[mf][nf][r];
                if (d < 32) *(bf16x4*)(Pqb + ((size_t)b * NN + n) * ND + d) = q4;
                else        *(bf16x4*)(Pkb + ((size_t)b * NN + n) * ND + d - 32) = q4;
            }
        }
    }
}

// ---------------------------------------------------------------------------
// Kernel 2: GEMM-shaped attention (R14 structure — best measured: 163.5 us).
// Block = (batch, 256-m chunk), 8 waves, 1 block/CU, 128 KB LDS.
// Step t: pv-ks0(t) | stageV(t+1)+qk(t+1) | loadK(t+2) | pv-ks1(t) | barrier.
// Producer phase between the two PV MFMA clusters so co-resident waves'
// VALU and MFMA windows tile instead of colliding in barrier lockstep.
// ps accumulation split into per-nt-parity partials (halved dep chain).
// ---------------------------------------------------------------------------
__global__ __launch_bounds__(512, 2) void attn_mfma(
    const bf16_t* __restrict__ Pqb,   // keys    K [B][N][32]
    const bf16_t* __restrict__ Pkb,   // queries Q [B][N][32] (pre-scaled log2e)
    const bf16_t* __restrict__ Vn,    // V [B][C][N]
    const float* __restrict__ x,
    const float* __restrict__ gamma_p,
    float* __restrict__ y)
{
    __shared__ bf16_t vlds[2][256*64];    // 64 KB V tiles, swizzled
    __shared__ bf16_t plds[2][256*64];    // 64 KB P tiles, swizzled

    const int wg  = blockIdx.x;
    const int swb = (wg & 7) * 32 + (wg >> 3);
    const int b   = swb >> 4;
    const int m0  = (swb & 15) << 8;

    const int tid  = threadIdx.x;
    const int lane = tid & 63;
    const int w    = tid >> 6;            // 0..7
    const int lhi  = lane >> 4;
    const int llo  = lane & 15;
    const int wc   = w & 3;               // PV m-quarter
    const int eh   = w >> 2;              // PV e-half

    const bf16_t* Kbase = Pqb + (size_t)b * NN * ND;
    const bf16_t* Vball = Vn  + (size_t)b * NC * NN;

    bf16x8 qa[2];
    #pragma unroll
    for (int mq = 0; mq < 2; ++mq)
        qa[mq] = *(const bf16x8*)(Pkb + ((size_t)(b*NN + m0 + w*32 + mq*16 + llo)) * ND + lhi*8);

    f32x4 acc[8][4];                      // [et][mt]
    #pragma unroll
    for (int et = 0; et < 8; ++et)
        #pragma unroll
        for (int mt = 0; mt < 4; ++mt)
            acc[et][mt] = (f32x4){0.f,0.f,0.f,0.f};

    float psl[2][2] = {{0.f,0.f},{0.f,0.f}};   // [mq][nt&1] partial denominators
    bf16x8 kb[4];
    const int swz = (llo & 7) << 4;

    const int r8  = lane >> 3;
    const int nsw = 8 * ((lane & 7) ^ r8);
    auto stageV = [&](int tt, int bufw) {
        #pragma unroll
        for (int i = 0; i < 4; ++i) {
            const int row0 = w*32 + i*8;
            const bf16_t* src = Vball + (size_t)(row0 + r8) * NN + tt*64 + nsw;
            bf16_t* dst = &vlds[bufw][row0 * 64];
            __builtin_amdgcn_global_load_lds(
                (const AS_GLOBAL unsigned int*)src,
                (AS_LDS unsigned int*)dst, 16, 0, 0);
        }
    };

    auto loadK = [&](int tt) {
        #pragma unroll
        for (int nt = 0; nt < 4; ++nt)
            kb[nt] = *(const bf16x8*)(Kbase + (size_t)(tt*64 + nt*16 + llo) * ND + lhi*8);
    };

    auto qk_phase = [&](int bufw) {
        f32x4 s[4][2];
        #pragma unroll
        for (int nt = 0; nt < 4; ++nt)
            #pragma unroll
            for (int mq = 0; mq < 2; ++mq)
                s[nt][mq] = __builtin_amdgcn_mfma_f32_16x16x32_bf16(kb[nt], qa[mq],
                                (f32x4){0.f,0.f,0.f,0.f}, 0, 0, 0);
        char* base = (char*)&plds[bufw][0] + (size_t)(w*32 + llo) * 128;
        #pragma unroll
        for (int mq = 0; mq < 2; ++mq)
            #pragma unroll
            for (int nt = 0; nt < 4; ++nt) {
                bf16x4 q4;
                float p0 = __builtin_amdgcn_exp2f(s[nt][mq][0]);
                float p1 = __builtin_amdgcn_exp2f(s[nt][mq][1]);
                float p2 = __builtin_amdgcn_exp2f(s[nt][mq][2]);
                float p3 = __builtin_amdgcn_exp2f(s[nt][mq][3]);
                psl[mq][nt & 1] += (p0 + p1) + (p2 + p3);
                q4[0] = (bf16_t)p0; q4[1] = (bf16_t)p1;
                q4[2] = (bf16_t)p2; q4[3] = (bf16_t)p3;
                *(bf16x4*)(base + mq*2048 + ((nt*32 + lhi*8) ^ swz)) = q4;
            }
    };

    // one ks-half of PV: 4 pf + 8 va ds_reads + 32 MFMA
    auto pv_ks = [&](int bufw, int ks) {
        char* vb = (char*)&vlds[bufw][0];
        char* pb = (char*)&plds[bufw][0];
        const int cofs = (ks*64 + lhi*16) ^ swz;
        bf16x8 pf[4];
        #pragma unroll
        for (int mt = 0; mt < 4; ++mt) {
            const int row = wc*64 + mt*16 + llo;
            pf[mt] = *(const bf16x8*)(pb + (size_t)row*128 + cofs);
        }
        bf16x8 va[8];
        #pragma unroll
        for (int ei = 0; ei < 8; ++ei) {
            const int row = eh*128 + ei*16 + llo;
            va[ei] = *(const bf16x8*)(vb + (size_t)row*128 + cofs);
        }
        __builtin_amdgcn_s_setprio(1);
        #pragma unroll
        for (int ei = 0; ei < 8; ++ei)
            #pragma unroll
            for (int mt = 0; mt < 4; ++mt)
                acc[ei][mt] = __builtin_amdgcn_mfma_f32_16x16x32_bf16(
                                  va[ei], pf[mt], acc[ei][mt], 0, 0, 0);
        __builtin_amdgcn_s_setprio(0);
    };

    // ---- prologue: V(0) DMA, K(0), P(0) -> buf0, K(1) in flight
    stageV(0, 0);
    loadK(0);
    qk_phase(0);
    loadK(1);
    __syncthreads();                      // V(0) + P(0) ready

    // ---- main loop: one barrier per step, producer phase between PV halves
    for (int t = 0; t < NN/64; ++t) {
        const int cur = t & 1;
        const int nxt = cur ^ 1;
        pv_ks(cur, 0);                    // first PV MFMA cluster
        if (t < NN/64 - 1) {
            stageV(t + 1, nxt);           // async DMA, drained at barrier
            qk_phase(nxt);                // kb holds K(t+1)
        }
        if (t < NN/64 - 2) loadK(t + 2);
        pv_ks(cur, 1);                    // second PV MFMA cluster
        __syncthreads();
    }

    // ---- denominators (alias dead vlds as float scratch)
    float* sum_lds = (float*)&vlds[0][0];
    #pragma unroll
    for (int mq = 0; mq < 2; ++mq) {
        float v = psl[mq][0] + psl[mq][1];
        v += __shfl_xor(v, 16, 64);
        v += __shfl_xor(v, 32, 64);
        if (lhi == 0) sum_lds[w*32 + mq*16 + llo] = v;
    }
    __syncthreads();

    const float gamma = gamma_p[0];
    float inv[4];
    #pragma unroll
    for (int mt = 0; mt < 4; ++mt) inv[mt] = 1.f / sum_lds[wc*64 + mt*16 + llo];

    #pragma unroll
    for (int et = 0; et < 8; ++et)
        #pragma unroll
        for (int mt = 0; mt < 4; ++mt) {
            const int m = m0 + wc*64 + mt*16 + llo;
            #pragma unroll
            for (int r = 0; r < 4; ++r) {
                const int e = eh*128 + et*16 + lhi*4 + r;
                size_t idx = ((size_t)(b*NC + e)) * NN + m;
                y[idx] = gamma * (acc[et][mt][r] * inv[mt]) + x[idx];
            }
        }
}

// ---------------------------------------------------------------------------
extern "C" void kernel_launch(void* const* d_in, const int* in_sizes, int n_in,
                              void* d_out, int out_size, void* d_ws, size_t ws_size,
                              hipStream_t stream) {
    const float* x     = (const float*)d_in[0];
    const float* Wq    = (const float*)d_in[1];
    const float* Wk    = (const float*)d_in[2];
    const float* Wv    = (const float*)d_in[3];
    const float* gamma = (const float*)d_in[4];
    float* y = (float*)d_out;

    bf16_t* Pqb = (bf16_t*)d_ws;
    bf16_t* Pkb = Pqb + (size_t)NB * NN * ND;
    bf16_t* Vnb = Pkb + (size_t)NB * NN * ND;
    bf16_t* Wb  = Vnb + (size_t)NB * NC * NN;
    bf16_t* Wlo = Wb  + 320 * 256;

    wconv<<<320, 256, 0, stream>>>(Wq, Wk, Wv, Wb, Wlo);
    proj_mfma<<<NB * (NN / BN_P), 512, 0, stream>>>(x, Wb, Wlo, Pqb, Pkb, Vnb);
    attn_mfma<<<NB * (NN/256), 512, 0, stream>>>(Pqb, Pkb, Vnb, x, gamma, y);
}

// Round 18
// 196.358 us; speedup vs baseline: 1.0833x; 1.0268x over previous
//
#include <hip/hip_runtime.h>
#include <math.h>
#include <stdint.h>

#define NB 16
#define NC 256
#define NN 4096
#define ND 32

typedef __bf16 bf16_t;
typedef __bf16 bf16x4 __attribute__((ext_vector_type(4)));
typedef __bf16 bf16x8 __attribute__((ext_vector_type(8)));
typedef float  f32x4  __attribute__((ext_vector_type(4)));

#define AS_GLOBAL __attribute__((address_space(1)))
#define AS_LDS    __attribute__((address_space(3)))

// ---------------------------------------------------------------------------
// Kernel 0: convert weights to bf16 (+ lo residuals for q/k rows), in the
// STRIP-INTERLEAVED layout: strip s (s=0..3) owns Wb rows [s*80, s*80+80):
//   rows s*80 + [0,64)  = Wv rows s*64 + [0,64)
//   rows s*80 + [64,80) = qk rows s*16 + [0,16)   (qk: 0-31 = Wq (xlog2e),
//                                                  32-63 = Wk)
// Wlo[qr][c] = lo residual of qk row qr (0..63).
// This balances the hi/lo correction MFMAs evenly across all 4 m-strips.
// ---------------------------------------------------------------------------
__global__ __launch_bounds__(256) void wconv(
    const float* __restrict__ Wq, const float* __restrict__ Wk,
    const float* __restrict__ Wv, bf16_t* __restrict__ Wb, bf16_t* __restrict__ Wlo)
{
    int i = blockIdx.x * 256 + threadIdx.x;
    if (i >= 320 * 256) return;
    int row = i >> 8, c = i & 255;
    int s = row / 80, within = row % 80;
    float v;
    int qr = -1;
    if (within < 64) {
        v = Wv[(s * 64 + within) * 256 + c];
    } else {
        qr = s * 16 + (within - 64);          // 0..63
        if (qr < 32) v = Wq[qr * 256 + c] * 1.44269504088896340736f;
        else         v = Wk[(qr - 32) * 256 + c];
    }
    bf16_t h = (bf16_t)v;
    Wb[i] = h;
    if (qr >= 0) Wlo[qr * 256 + c] = (bf16_t)(v - (float)h);
}

// ---------------------------------------------------------------------------
// Kernel 1: fused q/k/v projection, strip-balanced.
// Per (k0,ks,nf) every wave issues a uniform 7 MFMA:
//   mf=0..3 : Wv rows, Ah*bh
//   mf=4    : qk rows, Ah*bh + Al*bh + Ah*bl   (hi/lo compensated)
// ---------------------------------------------------------------------------
#define BN_P  128
#define KSTEP 64
#define XPAD  130

__global__ __launch_bounds__(512) void proj_mfma(
    const float* __restrict__ x, const bf16_t* __restrict__ Wb,
    const bf16_t* __restrict__ Wlo,
    bf16_t* __restrict__ Pqb, bf16_t* __restrict__ Pkb, bf16_t* __restrict__ Vn)
{
    __shared__ float xt[KSTEP][XPAD];

    const int b  = blockIdx.x >> 5;
    const int n0 = (blockIdx.x & 31) * BN_P;
    const int tid  = threadIdx.x;
    const int lane = tid & 63;
    const int w    = tid >> 6;
    const int mstrip = w >> 1;
    const int nh     = w & 1;
    const int llo = lane & 15, lhi = lane >> 4;

    const float* xb = x + (size_t)b * NC * NN + n0;

    f32x4 acc[5][4];
    #pragma unroll
    for (int mf = 0; mf < 5; ++mf)
        #pragma unroll
        for (int nf = 0; nf < 4; ++nf)
            acc[mf][nf] = (f32x4){0.f,0.f,0.f,0.f};

    for (int k0 = 0; k0 < NC; k0 += KSTEP) {
        #pragma unroll
        for (int p = 0; p < 4; ++p) {
            int idx = p * 512 + tid;
            int c   = idx >> 5;
            int nn  = (idx & 31) << 2;
            float4 v = *(const float4*)(xb + (size_t)(k0 + c) * NN + nn);
            *(float2*)&xt[c][nn]     = make_float2(v.x, v.y);
            *(float2*)&xt[c][nn + 2] = make_float2(v.z, v.w);
        }
        __syncthreads();

        #pragma unroll
        for (int ks = 0; ks < 2; ++ks) {
            bf16x8 Ah[5], Al;
            #pragma unroll
            for (int mf = 0; mf < 5; ++mf) {
                int row = mstrip * 80 + mf * 16 + llo;
                Ah[mf] = *(const bf16x8*)(Wb + (size_t)row * NC + k0 + ks * 32 + lhi * 8);
            }
            {
                int qr = mstrip * 16 + llo;       // qk row for mf=4
                Al = *(const bf16x8*)(Wlo + (size_t)qr * NC + k0 + ks * 32 + lhi * 8);
            }

            #pragma unroll
            for (int nf = 0; nf < 4; ++nf) {
                const int n  = nh * 64 + nf * 16 + llo;
                const int cb = ks * 32 + lhi * 8;
                bf16x8 bh, bl;
                #pragma unroll
                for (int j = 0; j < 8; ++j) {
                    float f = xt[cb + j][n];
                    bf16_t h = (bf16_t)f;
                    bh[j] = h;
                    bl[j] = (bf16_t)(f - (float)h);
                }
                #pragma unroll
                for (int mf = 0; mf < 4; ++mf)
                    acc[mf][nf] = __builtin_amdgcn_mfma_f32_16x16x32_bf16(
                                      Ah[mf], bh, acc[mf][nf], 0, 0, 0);
                acc[4][nf] = __builtin_amdgcn_mfma_f32_16x16x32_bf16(
                                  Ah[4], bh, acc[4][nf], 0, 0, 0);
                acc[4][nf] = __builtin_amdgcn_mfma_f32_16x16x32_bf16(
                                  Al,    bh, acc[4][nf], 0, 0, 0);
                acc[4][nf] = __builtin_amdgcn_mfma_f32_16x16x32_bf16(
                                  Ah[4], bl, acc[4][nf], 0, 0, 0);
            }
        }
        __syncthreads();
    }

    // epilogue: mf<4 -> Vn rows mstrip*64+...; mf=4 -> Pqb/Pkb (qk rows)
    #pragma unroll
    for (int mf = 0; mf < 5; ++mf) {
        #pragma unroll
        for (int nf = 0; nf < 4; ++nf) {
            const int n = n0 + nh * 64 + nf * 16 + llo;
            if (mf < 4) {
                const int e0 = mstrip * 64 + mf * 16 + lhi * 4;
                #pragma unroll
                for (int r = 0; r < 4; ++r)
                    Vn[((size_t)b * NC + e0 + r) * NN + n] = (bf16_t)acc[mf][nf][r];
            } else {
                const int qr = mstrip * 16 + lhi * 4;     // 0..60, 4-aligned
                bf16x4 q4;
                #pragma unroll
                for (int r = 0; r < 4; ++r) q4[r] = (bf16_t)acc[mf][nf][r];
                if (qr < 32) *(bf16x4*)(Pqb + ((size_t)b * NN + n) * ND + qr) = q4;
                else         *(bf16x4*)(Pkb + ((size_t)b * NN + n) * ND + qr - 32) = q4;
            }
        }
    }
}

// ---------------------------------------------------------------------------
// Kernel 2: GEMM-shaped attention (R14/R17 structure — stable 162-163 us).
// Block = (batch, 256-m chunk), 8 waves, 1 block/CU, 128 KB LDS.
// Step t: pv-ks0(t) | stageV(t+1)+qk(t+1) | loadK(t+2) | pv-ks1(t) | barrier.
// ---------------------------------------------------------------------------
__global__ __launch_bounds__(512, 2) void attn_mfma(
    const bf16_t* __restrict__ Pqb,   // keys    K [B][N][32]
    const bf16_t* __restrict__ Pkb,   // queries Q [B][N][32] (pre-scaled log2e)
    const bf16_t* __restrict__ Vn,    // V [B][C][N]
    const float* __restrict__ x,
    const float* __restrict__ gamma_p,
    float* __restrict__ y)
{
    __shared__ bf16_t vlds[2][256*64];    // 64 KB V tiles, swizzled
    __shared__ bf16_t plds[2][256*64];    // 64 KB P tiles, swizzled

    const int wg  = blockIdx.x;
    const int swb = (wg & 7) * 32 + (wg >> 3);
    const int b   = swb >> 4;
    const int m0  = (swb & 15) << 8;

    const int tid  = threadIdx.x;
    const int lane = tid & 63;
    const int w    = tid >> 6;            // 0..7
    const int lhi  = lane >> 4;
    const int llo  = lane & 15;
    const int wc   = w & 3;               // PV m-quarter
    const int eh   = w >> 2;              // PV e-half

    const bf16_t* Kbase = Pqb + (size_t)b * NN * ND;
    const bf16_t* Vball = Vn  + (size_t)b * NC * NN;

    bf16x8 qa[2];
    #pragma unroll
    for (int mq = 0; mq < 2; ++mq)
        qa[mq] = *(const bf16x8*)(Pkb + ((size_t)(b*NN + m0 + w*32 + mq*16 + llo)) * ND + lhi*8);

    f32x4 acc[8][4];                      // [et][mt]
    #pragma unroll
    for (int et = 0; et < 8; ++et)
        #pragma unroll
        for (int mt = 0; mt < 4; ++mt)
            acc[et][mt] = (f32x4){0.f,0.f,0.f,0.f};

    float psl[2][2] = {{0.f,0.f},{0.f,0.f}};   // [mq][nt&1] partial denominators
    bf16x8 kb[4];
    const int swz = (llo & 7) << 4;

    const int r8  = lane >> 3;
    const int nsw = 8 * ((lane & 7) ^ r8);
    auto stageV = [&](int tt, int bufw) {
        #pragma unroll
        for (int i = 0; i < 4; ++i) {
            const int row0 = w*32 + i*8;
            const bf16_t* src = Vball + (size_t)(row0 + r8) * NN + tt*64 + nsw;
            bf16_t* dst = &vlds[bufw][row0 * 64];
            __builtin_amdgcn_global_load_lds(
                (const AS_GLOBAL unsigned int*)src,
                (AS_LDS unsigned int*)dst, 16, 0, 0);
        }
    };

    auto loadK = [&](int tt) {
        #pragma unroll
        for (int nt = 0; nt < 4; ++nt)
            kb[nt] = *(const bf16x8*)(Kbase + (size_t)(tt*64 + nt*16 + llo) * ND + lhi*8);
    };

    auto qk_phase = [&](int bufw) {
        f32x4 s[4][2];
        #pragma unroll
        for (int nt = 0; nt < 4; ++nt)
            #pragma unroll
            for (int mq = 0; mq < 2; ++mq)
                s[nt][mq] = __builtin_amdgcn_mfma_f32_16x16x32_bf16(kb[nt], qa[mq],
                                (f32x4){0.f,0.f,0.f,0.f}, 0, 0, 0);
        char* base = (char*)&plds[bufw][0] + (size_t)(w*32 + llo) * 128;
        #pragma unroll
        for (int mq = 0; mq < 2; ++mq)
            #pragma unroll
            for (int nt = 0; nt < 4; ++nt) {
                bf16x4 q4;
                float p0 = __builtin_amdgcn_exp2f(s[nt][mq][0]);
                float p1 = __builtin_amdgcn_exp2f(s[nt][mq][1]);
                float p2 = __builtin_amdgcn_exp2f(s[nt][mq][2]);
                float p3 = __builtin_amdgcn_exp2f(s[nt][mq][3]);
                psl[mq][nt & 1] += (p0 + p1) + (p2 + p3);
                q4[0] = (bf16_t)p0; q4[1] = (bf16_t)p1;
                q4[2] = (bf16_t)p2; q4[3] = (bf16_t)p3;
                *(bf16x4*)(base + mq*2048 + ((nt*32 + lhi*8) ^ swz)) = q4;
            }
    };

    // one ks-half of PV: 4 pf + 8 va ds_reads + 32 MFMA
    auto pv_ks = [&](int bufw, int ks) {
        char* vb = (char*)&vlds[bufw][0];
        char* pb = (char*)&plds[bufw][0];
        const int cofs = (ks*64 + lhi*16) ^ swz;
        bf16x8 pf[4];
        #pragma unroll
        for (int mt = 0; mt < 4; ++mt) {
            const int row = wc*64 + mt*16 + llo;
            pf[mt] = *(const bf16x8*)(pb + (size_t)row*128 + cofs);
        }
        bf16x8 va[8];
        #pragma unroll
        for (int ei = 0; ei < 8; ++ei) {
            const int row = eh*128 + ei*16 + llo;
            va[ei] = *(const bf16x8*)(vb + (size_t)row*128 + cofs);
        }
        __builtin_amdgcn_s_setprio(1);
        #pragma unroll
        for (int ei = 0; ei < 8; ++ei)
            #pragma unroll
            for (int mt = 0; mt < 4; ++mt)
                acc[ei][mt] = __builtin_amdgcn_mfma_f32_16x16x32_bf16(
                                  va[ei], pf[mt], acc[ei][mt], 0, 0, 0);
        __builtin_amdgcn_s_setprio(0);
    };

    // ---- prologue: V(0) DMA, K(0), P(0) -> buf0, K(1) in flight
    stageV(0, 0);
    loadK(0);
    qk_phase(0);
    loadK(1);
    __syncthreads();                      // V(0) + P(0) ready

    // ---- main loop: one barrier per step, producer phase between PV halves
    for (int t = 0; t < NN/64; ++t) {
        const int cur = t & 1;
        const int nxt = cur ^ 1;
        pv_ks(cur, 0);                    // first PV MFMA cluster
        if (t < NN/64 - 1) {
            stageV(t + 1, nxt);           // async DMA, drained at barrier
            qk_phase(nxt);                // kb holds K(t+1)
        }
        if (t < NN/64 - 2) loadK(t + 2);
        pv_ks(cur, 1);                    // second PV MFMA cluster
        __syncthreads();
    }

    // ---- denominators (alias dead vlds as float scratch)
    float* sum_lds = (float*)&vlds[0][0];
    #pragma unroll
    for (int mq = 0; mq < 2; ++mq) {
        float v = psl[mq][0] + psl[mq][1];
        v += __shfl_xor(v, 16, 64);
        v += __shfl_xor(v, 32, 64);
        if (lhi == 0) sum_lds[w*32 + mq*16 + llo] = v;
    }
    __syncthreads();

    const float gamma = gamma_p[0];
    float inv[4];
    #pragma unroll
    for (int mt = 0; mt < 4; ++mt) inv[mt] = 1.f / sum_lds[wc*64 + mt*16 + llo];

    #pragma unroll
    for (int et = 0; et < 8; ++et)
        #pragma unroll
        for (int mt = 0; mt < 4; ++mt) {
            const int m = m0 + wc*64 + mt*16 + llo;
            #pragma unroll
            for (int r = 0; r < 4; ++r) {
                const int e = eh*128 + et*16 + lhi*4 + r;
                size_t idx = ((size_t)(b*NC + e)) * NN + m;
                y[idx] = gamma * (acc[et][mt][r] * inv[mt]) + x[idx];
            }
        }
}

// ---------------------------------------------------------------------------
extern "C" void kernel_launch(void* const* d_in, const int* in_sizes, int n_in,
                              void* d_out, int out_size, void* d_ws, size_t ws_size,
                              hipStream_t stream) {
    const float* x     = (const float*)d_in[0];
    const float* Wq    = (const float*)d_in[1];
    const float* Wk    = (const float*)d_in[2];
    const float* Wv    = (const float*)d_in[3];
    const float* gamma = (const float*)d_in[4];
    float* y = (float*)d_out;

    bf16_t* Pqb = (bf16_t*)d_ws;
    bf16_t* Pkb = Pqb + (size_t)NB * NN * ND;
    bf16_t* Vnb = Pkb + (size_t)NB * NN * ND;
    bf16_t* Wb  = Vnb + (size_t)NB * NC * NN;
    bf16_t* Wlo = Wb  + 320 * 256;

    wconv<<<320, 256, 0, stream>>>(Wq, Wk, Wv, Wb, Wlo);
    proj_mfma<<<NB * (NN / BN_P), 512, 0, stream>>>(x, Wb, Wlo, Pqb, Pkb, Vnb);
    attn_mfma<<<NB * (NN/256), 512, 0, stream>>>(Pqb, Pkb, Vnb, x, gamma, y);
}